// Round 1
// baseline (236.561 us; speedup 1.0000x reference)
//
#include <hip/hip_runtime.h>

// Problem constants
#define MD 4
#define PATCH 9          // 2*MD+1
// feat1/feat2: (4, 256, 64, 64) fp32
// out: (4, 4096, 64, 64) fp32 = 256 MB
//
// out[b, ty*64+tx, y, x] = sum_c f1[b,c,y,x] * f2[b,c,ty,tx]  if |ty-y|<=4 && |tx-x|<=4, else 0.

__global__ __launch_bounds__(256, 1) void cv_kernel(
    const float* __restrict__ f1,
    const float* __restrict__ f2,
    float* __restrict__ out)
{
    const int bty = blockIdx.x;       // 0..255
    const int b   = bty >> 6;         // 0..3
    const int ty  = bty & 63;         // 0..63
    const int tid  = threadIdx.x;     // 0..255
    const int lane = tid & 63;        // u = x position
    const int wq   = tid >> 6;        // wave id: channel quarter

    // sVals[tx][dyi*9+dxi] = val(tx, y=ty+dyi-4, x=tx+dxi-4)
    __shared__ float sVals[64][81];   // 20.7 KB; stride 81 = 17 mod 32 -> conflict-free

    // zero the LDS accumulator
    for (int i = tid; i < 64 * 81; i += 256)
        (&sVals[0][0])[i] = 0.0f;

    const int q  = tid & 15;          // float4 index within a 64-float row
    const int ro = tid >> 4;          // row offset 0..15

    // block-owned output slab: t in [ty*64, ty*64+64), 1 MB contiguous
    float4* out4 = (float4*)(out + (size_t)(b * 4096 + ty * 64) * 4096);
    const float4 z4 = make_float4(0.f, 0.f, 0.f, 0.f);

    // ---- Loop A: rows with |y - ty| > MD are entirely zero (~86% of bytes).
    // Issue these stores first so HBM drain overlaps the compute phase.
    for (int rb = 0; rb < 4096; rb += 16) {
        int row = rb + ro;            // row = tx*64 + y
        int y   = row & 63;
        int dy  = y - ty;
        if (dy < -MD || dy > MD) {
            int tx = row >> 6;
            out4[tx * 1024 + y * 16 + q] = z4;
        }
    }

    __syncthreads();   // sVals zeroing complete

    // ---- Phase 1: per-wave channel-partial correlation.
    // Lane u accumulates acc[dyi][dxi] = sum_c f1[c, ty+dyi-4, u] * f2[c, ty, u-(dxi-4)]
    //   == val(tx = u-(dxi-4), y = ty+dyi-4, x = u)
    float acc[PATCH][PATCH];
#pragma unroll
    for (int i = 0; i < PATCH; ++i)
#pragma unroll
        for (int j = 0; j < PATCH; ++j) acc[i][j] = 0.f;

    const float* f1p = f1 + (size_t)(b * 256 + wq * 64) * 4096 + lane;
    const float* f2p = f2 + (size_t)(b * 256 + wq * 64) * 4096 + ty * 64 + lane;

    for (int c = 0; c < 64; ++c) {
        float f2v = f2p[(size_t)c * 4096];
        float sh[PATCH];
#pragma unroll
        for (int dxi = 0; dxi < PATCH; ++dxi)
            sh[dxi] = __shfl(f2v, lane - (dxi - MD), 64);   // f2[c, ty, u-dx]
#pragma unroll
        for (int dyi = 0; dyi < PATCH; ++dyi) {
            int y = ty + dyi - MD;
            if ((unsigned)y < 64u) {                        // uniform branch per block
                float f1v = f1p[(size_t)c * 4096 + y * 64]; // f1[c, y, u], coalesced
#pragma unroll
                for (int dxi = 0; dxi < PATCH; ++dxi)
                    acc[dyi][dxi] = fmaf(f1v, sh[dxi], acc[dyi][dxi]);
            }
        }
    }

    // Merge the 4 wave partials: lane u owns tx = u - (dxi-4)
#pragma unroll
    for (int dyi = 0; dyi < PATCH; ++dyi) {
        int y = ty + dyi - MD;
        if ((unsigned)y >= 64u) continue;
#pragma unroll
        for (int dxi = 0; dxi < PATCH; ++dxi) {
            int tx = lane - (dxi - MD);
            if ((unsigned)tx < 64u)
                atomicAdd(&sVals[tx][dyi * PATCH + dxi], acc[dyi][dxi]);
        }
    }

    __syncthreads();

    // ---- Loop B: rows with |y - ty| <= MD: mix of zeros and the 9-wide value band.
    for (int rb = 0; rb < 64 * PATCH; rb += 16) {
        int row = rb + ro;            // row = tx*9 + dyi
        int tx  = row / PATCH;        // const divisor -> magic multiply
        int dyi = row - tx * PATCH;
        int y   = ty + dyi - MD;
        if ((unsigned)y < 64u) {
            float comp[4];
#pragma unroll
            for (int j = 0; j < 4; ++j) {
                int x  = q * 4 + j;
                int dx = x - tx;
                comp[j] = (dx >= -MD && dx <= MD) ? sVals[tx][dyi * PATCH + dx + MD] : 0.f;
            }
            out4[tx * 1024 + y * 16 + q] = make_float4(comp[0], comp[1], comp[2], comp[3]);
        }
    }
}

extern "C" void kernel_launch(void* const* d_in, const int* in_sizes, int n_in,
                              void* d_out, int out_size, void* d_ws, size_t ws_size,
                              hipStream_t stream) {
    const float* f1 = (const float*)d_in[0];
    const float* f2 = (const float*)d_in[1];
    float* out = (float*)d_out;
    cv_kernel<<<256, 256, 0, stream>>>(f1, f2, out);
}

// Round 2
// 235.807 us; speedup vs baseline: 1.0032x; 1.0032x over previous
//
#include <hip/hip_runtime.h>

// Problem constants
#define MD 4
#define PATCH 9          // 2*MD+1
#define NBAND 256        // band-compute blocks: (b, ty) = 4 * 64
#define NZERO 4096       // zero-streaming blocks
// feat1/feat2: (4, 256, 64, 64) fp32
// out: (4, 4096, 64, 64) fp32 = 256 MB
//
// out[b, ty*64+tx, y, x] = sum_c f1[b,c,y,x] * f2[b,c,ty,tx]  if |ty-y|<=4 && |tx-x|<=4, else 0.
//
// Row-level partition (disjoint, exhaustive):
//   zero blocks write rows (b,t,y) with |y - ty| > 4   (~220 MB, pure store stream)
//   band blocks write rows (b,t,y) with |y - ty| <= 4  (~36 MB, computed)

__global__ __launch_bounds__(256, 4) void cv_kernel(
    const float* __restrict__ f1,
    const float* __restrict__ f2,
    float* __restrict__ out)
{
    const int tid = threadIdx.x;

    // ---------------- zero-streaming blocks ----------------
    if (blockIdx.x >= NBAND) {
        // grid-stride over all float4s of out; write zeros to non-band rows.
        // float4 index i: bits [0:4)=x4, [4:10)=y, [10:22)=t (ty = bits 16..22), [22:24)=b
        float4* o4 = (float4*)out;
        const float4 z4 = make_float4(0.f, 0.f, 0.f, 0.f);
        const int total4 = 4 * 4096 * 64 * 16;            // 16,777,216
        const int stride = NZERO * 256;
        for (int i = (blockIdx.x - NBAND) * 256 + tid; i < total4; i += stride) {
            int y  = (i >> 4) & 63;
            int ty = (i >> 16) & 63;
            int dy = y - ty;
            if (dy < -MD || dy > MD)
                o4[i] = z4;
        }
        return;
    }

    // ---------------- band-compute blocks ----------------
    const int bty = blockIdx.x;       // 0..255
    const int b   = bty >> 6;         // 0..3
    const int ty  = bty & 63;         // 0..63
    const int lane = tid & 63;        // u = x position
    const int wq   = tid >> 6;        // wave id: channel quarter

    // sVals[tx][dyi*9+dxi] = val(tx, y=ty+dyi-4, x=tx+dxi-4)
    __shared__ float sVals[64][81];   // 20.7 KB; stride 81 = 17 mod 32 -> conflict-free

    for (int i = tid; i < 64 * 81; i += 256)
        (&sVals[0][0])[i] = 0.0f;

    __syncthreads();

    // Phase 1: per-wave channel-partial correlation.
    // Lane u: acc[dyi][dxi] = sum_c f1[c, ty+dyi-4, u] * f2[c, ty, u-(dxi-4)]
    //   == val(tx = u-(dxi-4), y = ty+dyi-4, x = u)
    float acc[PATCH][PATCH];
#pragma unroll
    for (int i = 0; i < PATCH; ++i)
#pragma unroll
        for (int j = 0; j < PATCH; ++j) acc[i][j] = 0.f;

    const float* f1p = f1 + (size_t)(b * 256 + wq * 64) * 4096 + lane;
    const float* f2p = f2 + (size_t)(b * 256 + wq * 64) * 4096 + ty * 64 + lane;

    for (int c = 0; c < 64; ++c) {
        float f2v = f2p[(size_t)c * 4096];
        float sh[PATCH];
#pragma unroll
        for (int dxi = 0; dxi < PATCH; ++dxi)
            sh[dxi] = __shfl(f2v, lane - (dxi - MD), 64);   // f2[c, ty, u-dx]
#pragma unroll
        for (int dyi = 0; dyi < PATCH; ++dyi) {
            int y = ty + dyi - MD;
            if ((unsigned)y < 64u) {                        // uniform per block
                float f1v = f1p[(size_t)c * 4096 + y * 64]; // f1[c, y, u], coalesced
#pragma unroll
                for (int dxi = 0; dxi < PATCH; ++dxi)
                    acc[dyi][dxi] = fmaf(f1v, sh[dxi], acc[dyi][dxi]);
            }
        }
    }

    // Merge 4 wave partials: lane u owns tx = u - (dxi-4)
#pragma unroll
    for (int dyi = 0; dyi < PATCH; ++dyi) {
        int y = ty + dyi - MD;
        if ((unsigned)y >= 64u) continue;
#pragma unroll
        for (int dxi = 0; dxi < PATCH; ++dxi) {
            int tx = lane - (dxi - MD);
            if ((unsigned)tx < 64u)
                atomicAdd(&sVals[tx][dyi * PATCH + dxi], acc[dyi][dxi]);
        }
    }

    __syncthreads();

    // Band rows: full 64-float rows (9-wide value window, zeros elsewhere).
    float4* out4 = (float4*)(out + (size_t)(b * 4096 + ty * 64) * 4096);
    const int q  = tid & 15;          // float4 index within a row
    const int ro = tid >> 4;          // row offset 0..15
    for (int rb = 0; rb < 64 * PATCH; rb += 16) {
        int row = rb + ro;            // row = tx*9 + dyi
        int tx  = row / PATCH;        // const divisor -> magic multiply
        int dyi = row - tx * PATCH;
        int y   = ty + dyi - MD;
        if ((unsigned)y < 64u) {
            float comp[4];
#pragma unroll
            for (int j = 0; j < 4; ++j) {
                int x  = q * 4 + j;
                int dx = x - tx;
                comp[j] = (dx >= -MD && dx <= MD) ? sVals[tx][dyi * PATCH + dx + MD] : 0.f;
            }
            out4[tx * 1024 + y * 16 + q] = make_float4(comp[0], comp[1], comp[2], comp[3]);
        }
    }
}

extern "C" void kernel_launch(void* const* d_in, const int* in_sizes, int n_in,
                              void* d_out, int out_size, void* d_ws, size_t ws_size,
                              hipStream_t stream) {
    const float* f1 = (const float*)d_in[0];
    const float* f2 = (const float*)d_in[1];
    float* out = (float*)d_out;
    cv_kernel<<<NBAND + NZERO, 256, 0, stream>>>(f1, f2, out);
}

// Round 3
// 205.672 us; speedup vs baseline: 1.1502x; 1.1465x over previous
//
#include <hip/hip_runtime.h>

// Problem constants
#define MD 4
#define PATCH 9          // 2*MD+1
#define NBAND 256        // band-compute blocks: (b, ty) = 4 * 64
#define NZERO 4096       // zero-streaming blocks
// feat1/feat2: (4, 256, 64, 64) fp32
// out: (4, 4096, 64, 64) fp32 = 256 MB
//
// out[b, ty*64+tx, y, x] = sum_c f1[b,c,y,x] * f2[b,c,ty,tx]  if |ty-y|<=4 && |tx-x|<=4, else 0.
//
// Row-level partition (disjoint, exhaustive):
//   zero blocks write rows (b,t,y) with |y - ty| > 4   (~220 MB, pure store stream)
//   band blocks write rows (b,t,y) with |y - ty| <= 4  (~36 MB, computed)

__global__ __launch_bounds__(256, 4) void cv_kernel(
    const float* __restrict__ f1,
    const float* __restrict__ f2,
    float* __restrict__ out)
{
    const int tid = threadIdx.x;

    // ---------------- zero-streaming blocks ----------------
    if (blockIdx.x >= NBAND) {
        // grid-stride over all float4s of out; write zeros to non-band rows.
        // float4 index i: bits [0:4)=x4, [4:10)=y, [10:22)=t (ty = bits 16..22), [22:24)=b
        float4* o4 = (float4*)out;
        const float4 z4 = make_float4(0.f, 0.f, 0.f, 0.f);
        const int total4 = 4 * 4096 * 64 * 16;            // 16,777,216
        const int stride = NZERO * 256;
        for (int i = (blockIdx.x - NBAND) * 256 + tid; i < total4; i += stride) {
            int y  = (i >> 4) & 63;
            int ty = (i >> 16) & 63;
            int dy = y - ty;
            if (dy < -MD || dy > MD)
                o4[i] = z4;
        }
        return;
    }

    // ---------------- band-compute blocks ----------------
    const int bty = blockIdx.x;       // 0..255
    const int b   = bty >> 6;         // 0..3
    const int ty  = bty & 63;         // 0..63
    const int lane = tid & 63;        // u = x position
    const int wq   = tid >> 6;        // wave id: channel quarter

    // sVals[tx][dyi*9+dxi] = val(tx, y=ty+dyi-4, x=tx+dxi-4)
    __shared__ float sVals[64][81];   // 20.7 KB; stride 81 = 17 mod 32 -> conflict-free

    for (int i = tid; i < 64 * 81; i += 256)
        (&sVals[0][0])[i] = 0.0f;

    __syncthreads();

    // Phase 1: per-wave channel-partial correlation.
    // Lane u: acc[dyi][dxi] = sum_c f1[c, yc(dyi), u] * f2[c, ty, u-(dxi-4)]
    //   == val(tx = u-(dxi-4), y = ty+dyi-4, x = u)   for valid dyi.
    // KEY: all loads are unconditional (row index clamped to [0,63]); accumulators
    // for out-of-range dyi contain garbage and are DISCARDED at the merge step.
    // This lets the compiler batch all 10 global loads per channel behind one
    // s_waitcnt instead of nine serialized load->wait->use chains.
    float acc[PATCH][PATCH];
#pragma unroll
    for (int i = 0; i < PATCH; ++i)
#pragma unroll
        for (int j = 0; j < PATCH; ++j) acc[i][j] = 0.f;

    int off[PATCH];                   // clamped row byte offsets (in floats)
#pragma unroll
    for (int d = 0; d < PATCH; ++d) {
        int y = ty + d - MD;
        y = y < 0 ? 0 : (y > 63 ? 63 : y);
        off[d] = y * 64;
    }

    const float* f1p = f1 + (size_t)(b * 256 + wq * 64) * 4096 + lane;
    const float* f2p = f2 + (size_t)(b * 256 + wq * 64) * 4096 + ty * 64 + lane;

#pragma unroll 2
    for (int c = 0; c < 64; ++c) {
        const float* f1c = f1p + (size_t)c * 4096;
        float f2v = f2p[(size_t)c * 4096];
        float f1v[PATCH];
#pragma unroll
        for (int d = 0; d < PATCH; ++d)
            f1v[d] = f1c[off[d]];                           // 9 batched coalesced loads
        float sh[PATCH];
#pragma unroll
        for (int dxi = 0; dxi < PATCH; ++dxi)
            sh[dxi] = __shfl(f2v, lane - (dxi - MD), 64);   // f2[c, ty, u-dx]
#pragma unroll
        for (int dyi = 0; dyi < PATCH; ++dyi)
#pragma unroll
            for (int dxi = 0; dxi < PATCH; ++dxi)
                acc[dyi][dxi] = fmaf(f1v[dyi], sh[dxi], acc[dyi][dxi]);
    }

    // Merge 4 wave partials: lane u owns tx = u - (dxi-4). Invalid dyi skipped here.
#pragma unroll
    for (int dyi = 0; dyi < PATCH; ++dyi) {
        int y = ty + dyi - MD;
        if ((unsigned)y >= 64u) continue;
#pragma unroll
        for (int dxi = 0; dxi < PATCH; ++dxi) {
            int tx = lane - (dxi - MD);
            if ((unsigned)tx < 64u)
                atomicAdd(&sVals[tx][dyi * PATCH + dxi], acc[dyi][dxi]);
        }
    }

    __syncthreads();

    // Band rows: full 64-float rows (9-wide value window, zeros elsewhere).
    float4* out4 = (float4*)(out + (size_t)(b * 4096 + ty * 64) * 4096);
    const int q  = tid & 15;          // float4 index within a row
    const int ro = tid >> 4;          // row offset 0..15
    for (int rb = 0; rb < 64 * PATCH; rb += 16) {
        int row = rb + ro;            // row = tx*9 + dyi
        int tx  = row / PATCH;        // const divisor -> magic multiply
        int dyi = row - tx * PATCH;
        int y   = ty + dyi - MD;
        if ((unsigned)y < 64u) {
            float comp[4];
#pragma unroll
            for (int j = 0; j < 4; ++j) {
                int x  = q * 4 + j;
                int dx = x - tx;
                comp[j] = (dx >= -MD && dx <= MD) ? sVals[tx][dyi * PATCH + dx + MD] : 0.f;
            }
            out4[tx * 1024 + y * 16 + q] = make_float4(comp[0], comp[1], comp[2], comp[3]);
        }
    }
}

extern "C" void kernel_launch(void* const* d_in, const int* in_sizes, int n_in,
                              void* d_out, int out_size, void* d_ws, size_t ws_size,
                              hipStream_t stream) {
    const float* f1 = (const float*)d_in[0];
    const float* f2 = (const float*)d_in[1];
    float* out = (float*)d_out;
    cv_kernel<<<NBAND + NZERO, 256, 0, stream>>>(f1, f2, out);
}

// Round 4
// 169.580 us; speedup vs baseline: 1.3950x; 1.2128x over previous
//
#include <hip/hip_runtime.h>

// Problem constants
#define MD 4
#define PATCH 9          // 2*MD+1
#define NBAND 256        // band-compute blocks: (b, ty) = 4 * 64
#define NZERO 4096       // zero-streaming blocks
// feat1/feat2: (4, 256, 64, 64) fp32
// out: (4, 4096, 64, 64) fp32 = 256 MB
//
// out[b, ty*64+tx, y, x] = sum_c f1[b,c,y,x] * f2[b,c,ty,tx]  if |ty-y|<=4 && |tx-x|<=4, else 0.
//
// Row partition: zero blocks write rows |y-ty|>4 (~220 MB); band blocks write |y-ty|<=4 (~36 MB).
// Band block wave decomposition: wave wq owns dyi rows {0,1}/{2,3}/{4,5}/{6,7,8} over ALL 256
// channels -> max 27 accumulators/thread (no spill; previous 81-acc layout spilled at VGPR=64).

template<int ND>
__device__ __forceinline__ void band_work(
    const float* __restrict__ f1base,   // f1 + b*256*4096 + lane
    const float* __restrict__ f2base,   // f2 + b*256*4096 + ty*64 + lane
    int ty, int dy0, int lane,
    float (*sVals)[81])
{
    float acc[ND][PATCH];
#pragma unroll
    for (int i = 0; i < ND; ++i)
#pragma unroll
        for (int j = 0; j < PATCH; ++j) acc[i][j] = 0.f;

    int yoff[ND];                        // clamped row offsets (floats); invalid rows discarded later
#pragma unroll
    for (int i = 0; i < ND; ++i) {
        int y = ty + dy0 + i - MD;
        y = y < 0 ? 0 : (y > 63 ? 63 : y);
        yoff[i] = y * 64;
    }

#pragma unroll 4
    for (int c = 0; c < 256; ++c) {
        const float* f1c = f1base + (size_t)c * 4096;
        float f2v = f2base[(size_t)c * 4096];         // f2[c, ty, lane]
        float f1v[ND];
#pragma unroll
        for (int i = 0; i < ND; ++i)
            f1v[i] = f1c[yoff[i]];                    // batched coalesced loads
        float sh[PATCH];
#pragma unroll
        for (int dxi = 0; dxi < PATCH; ++dxi)
            sh[dxi] = __shfl(f2v, lane - (dxi - MD), 64);   // f2[c, ty, u-dx]
#pragma unroll
        for (int i = 0; i < ND; ++i)
#pragma unroll
            for (int dxi = 0; dxi < PATCH; ++dxi)
                acc[i][dxi] = fmaf(f1v[i], sh[dxi], acc[i][dxi]);
    }

    // Direct LDS write: this wave exclusively owns its (dyi, dxi) entries.
    // Entry (tx, dxi) written iff lane = tx + dxi - 4 in [0,64) -- exactly the set loop B reads.
#pragma unroll
    for (int i = 0; i < ND; ++i) {
        int dyi = dy0 + i;
        int y = ty + dyi - MD;
        if ((unsigned)y >= 64u) continue;             // uniform per wave
#pragma unroll
        for (int dxi = 0; dxi < PATCH; ++dxi) {
            int tx = lane - (dxi - MD);
            if ((unsigned)tx < 64u)
                sVals[tx][dyi * PATCH + dxi] = acc[i][dxi];  // stride 81: conflict-free
        }
    }
}

__global__ __launch_bounds__(256, 4) void cv_kernel(
    const float* __restrict__ f1,
    const float* __restrict__ f2,
    float* __restrict__ out)
{
    const int tid = threadIdx.x;

    // ---------------- zero-streaming blocks ----------------
    if (blockIdx.x >= NBAND) {
        // float4 index i: bits [0:4)=x4, [4:10)=y, [10:16)=tx, [16:22)=ty, [22:24)=b
        float4* o4 = (float4*)out;
        const float4 z4 = make_float4(0.f, 0.f, 0.f, 0.f);
        const int total4 = 4 * 4096 * 64 * 16;            // 16,777,216
        const int stride = NZERO * 256;
        for (int i = (blockIdx.x - NBAND) * 256 + tid; i < total4; i += stride) {
            int y  = (i >> 4) & 63;
            int ty = (i >> 16) & 63;
            int dy = y - ty;
            if (dy < -MD || dy > MD)
                o4[i] = z4;
        }
        return;
    }

    // ---------------- band-compute blocks ----------------
    const int bty = blockIdx.x;       // 0..255
    const int b   = bty >> 6;         // 0..3
    const int ty  = bty & 63;         // 0..63
    const int lane = tid & 63;        // u = x position
    const int wq   = tid >> 6;        // wave id -> dyi subset

    // sVals[tx][dyi*9+dxi] = val(tx, y=ty+dyi-4, x=tx+dxi-4)
    __shared__ float sVals[64][81];   // 20.7 KB

    const float* f1base = f1 + (size_t)b * 256 * 4096 + lane;
    const float* f2base = f2 + (size_t)b * 256 * 4096 + ty * 64 + lane;

    if      (wq == 0) band_work<2>(f1base, f2base, ty, 0, lane, sVals);
    else if (wq == 1) band_work<2>(f1base, f2base, ty, 2, lane, sVals);
    else if (wq == 2) band_work<2>(f1base, f2base, ty, 4, lane, sVals);
    else              band_work<3>(f1base, f2base, ty, 6, lane, sVals);

    __syncthreads();

    // Band rows: full 64-float rows (9-wide value window, zeros elsewhere).
    float4* out4 = (float4*)(out + (size_t)(b * 4096 + ty * 64) * 4096);
    const int q  = tid & 15;          // float4 index within a row
    const int ro = tid >> 4;          // row offset 0..15
    for (int rb = 0; rb < 64 * PATCH; rb += 16) {
        int row = rb + ro;            // row = tx*9 + dyi
        int tx  = row / PATCH;        // const divisor -> magic multiply
        int dyi = row - tx * PATCH;
        int y   = ty + dyi - MD;
        if ((unsigned)y < 64u) {
            float comp[4];
#pragma unroll
            for (int j = 0; j < 4; ++j) {
                int x  = q * 4 + j;
                int dx = x - tx;
                comp[j] = (dx >= -MD && dx <= MD) ? sVals[tx][dyi * PATCH + dx + MD] : 0.f;
            }
            out4[tx * 1024 + y * 16 + q] = make_float4(comp[0], comp[1], comp[2], comp[3]);
        }
    }
}

extern "C" void kernel_launch(void* const* d_in, const int* in_sizes, int n_in,
                              void* d_out, int out_size, void* d_ws, size_t ws_size,
                              hipStream_t stream) {
    const float* f1 = (const float*)d_in[0];
    const float* f2 = (const float*)d_in[1];
    float* out = (float*)d_out;
    cv_kernel<<<NBAND + NZERO, 256, 0, stream>>>(f1, f2, out);
}